// Round 15
// baseline (102.898 us; speedup 1.0000x reference)
//
#include <hip/hip_runtime.h>

#define NEG  (-1e30f)
#define LN2F 0.69314718056f

// Problem dims (fixed by setup_inputs): B=16, TXT=128, MEL=512, NM=80
#define B_   16
#define TXT_ 128
#define MEL_ 512
#define NM_  80
#define IT_  8              // i-rows per lp block
#define PKB_ (MEL_ * TXT_)  // 65536 floats per batch in packed region

typedef float vf4 __attribute__((ext_vector_type(4)));

// ---------------------------------------------------------------------------
// Kernel 1: log_prob_matrix (exact R11-proven body). Zeroes out[0] and the
// per-b musum stash (separate array at ws+4MB).
// ---------------------------------------------------------------------------
__global__ __launch_bounds__(512) void lp_kernel(
    const float* __restrict__ mu_logvar,  // (B, TXT, 2*NM)
    const float* __restrict__ melspec,    // (B, NM, MEL)
    float* __restrict__ lp_out,           // (B, TXT, MEL)  = d_out + 1
    float* __restrict__ stash,            // (B,) musum accumulators in ws
    float* __restrict__ out0)             // d_out[0]
{
    const int i0 = blockIdx.x * IT_;
    const int b  = blockIdx.y;
    const int t  = threadIdx.x;

    __shared__ float2 s_wb[IT_][NM_];
    __shared__ float  s_cp[IT_ * NM_];
    __shared__ float  s_cc[IT_];

    for (int u = t; u < IT_ * NM_; u += 512) {   // 640 > 512: strided loop!
        int ii = u / NM_;
        int n  = u - ii * NM_;
        const float* row = mu_logvar + (size_t)(b * TXT_ + i0 + ii) * (2 * NM_);
        float mu = row[n];
        float lv = row[NM_ + n];
        float w  = __expf(-lv);
        s_wb[ii][n] = make_float2(w, -2.f * mu * w);
        s_cp[u]     = mu * mu * w + lv;
    }
    __syncthreads();
    if (t < IT_) {
        float c = 0.f;
        #pragma unroll
        for (int n = 0; n < NM_; ++n) c += s_cp[t * NM_ + n];
        s_cc[t] = c;
    }
    __syncthreads();

    const float* xcol = melspec + (size_t)b * NM_ * MEL_ + t;
    float acc[IT_];
    #pragma unroll
    for (int ii = 0; ii < IT_; ++ii) acc[ii] = 0.f;

    #pragma unroll 4
    for (int n = 0; n < NM_; ++n) {
        float x  = xcol[(size_t)n * MEL_];
        float x2 = x * x;
        #pragma unroll
        for (int ii = 0; ii < IT_; ++ii) {
            float2 wb = s_wb[ii][n];
            acc[ii] = fmaf(wb.x, x2, fmaf(wb.y, x, acc[ii]));
        }
    }

    const size_t rowbase = ((size_t)(b * TXT_ + i0)) * MEL_ + t;
    #pragma unroll
    for (int ii = 0; ii < IT_; ++ii) {
        lp_out[rowbase + (size_t)ii * MEL_] =
            (-0.5f / (float)NM_) * (acc[ii] + s_cc[ii]);
    }

    if (i0 == 0 && t == 0) stash[b] = 0.f;
    if (i0 == 0 && b == 0 && t == 0) *out0 = 0.f;
}

// ---------------------------------------------------------------------------
// Kernel 2: fused shift + exp + PACKED-PAIR transpose (R14 layout, audited).
//   mu_t = max_i lp[b][i][t];  w[t][i] = exp(lp[b][i][t] - mu_t - ln2)
//   P[b][p*256 + (i>>1)*4 + ((t-1)&1)*2 + (i&1)] = w[t][i],  p=(t-1)>>1
// Lane l's 16B packet at p*256+4l = both its columns for steps 2p+1, 2p+2.
// stash[b] += sum_{t in [1,TendM1]}(mu_t+ln2) (+ lp00). mu-shift is
// LOAD-BEARING (R10 post-mortem).
// ---------------------------------------------------------------------------
__global__ __launch_bounds__(256) void wt_kernel(
    const float* __restrict__ lp,   // (B, TXT, MEL) = d_out + 1
    const int* __restrict__ mel_len,
    float* __restrict__ wpk,        // (B, 65536) packed in ws
    float* __restrict__ stash)      // (B,) musum
{
    __shared__ float tileT[32][TXT_ + 1];   // [t_loc][i], pad breaks conflicts
    __shared__ float pmax[32][8];
    __shared__ float psum[32];

    const int t0  = blockIdx.x * 32;   // mel tile
    const int b   = blockIdx.y;
    const int tid = threadIdx.x;       // 0..255

    const float* src = lp + (size_t)b * TXT_ * MEL_ + t0;
    for (int u = tid; u < TXT_ * 32; u += 256) {
        int i = u >> 5, c = u & 31;
        tileT[c][i] = src[(size_t)i * MEL_ + c];
    }
    __syncthreads();

    {   // 8-way partial max over i per t_loc
        int tt = tid >> 3, g = tid & 7;
        float m = NEG;
        #pragma unroll
        for (int k = 0; k < 16; ++k) m = fmaxf(m, tileT[tt][g * 16 + k]);
        pmax[tt][g] = m;
    }
    __syncthreads();
    if (tid < 32) {
        float m = pmax[tid][0];
        #pragma unroll
        for (int g = 1; g < 8; ++g) m = fmaxf(m, pmax[tid][g]);
        pmax[tid][0] = m;                          // mu_t
        int tg = t0 + tid;
        int TendM1 = mel_len[b] - 1;
        psum[tid] = (tg >= 1 && tg <= TendM1) ? (m + LN2F) : 0.f;
    }
    __syncthreads();

    float* dstb = wpk + (size_t)b * PKB_;
    for (int u = tid; u < 32 * TXT_; u += 256) {
        int tt = u >> 7, i = u & 127;
        int tg = t0 + tt;
        if (tg >= 1) {
            int tm = tg - 1;
            size_t off = (size_t)(tm >> 1) * 256 + (i >> 1) * 4
                       + (tm & 1) * 2 + (i & 1);
            dstb[off] = __expf(tileT[tt][i] - pmax[tt][0] - LN2F);
        }
    }

    if (tid == 0) {
        float s = 0.f;
        #pragma unroll
        for (int k = 0; k < 32; ++k) s += psum[k];
        if (t0 == 0) s += tileT[0][0];             // + lp[b][0][0]
        atomicAdd(&stash[b], s);                   // musum
    }
}

// ---------------------------------------------------------------------------
// Kernel 3: linear-domain scan. R11 skeleton (single for-loop, per-step
// checked bookkeeping, 16 asm slots, VWAIT12 -- the R12/R13 while+tail
// split crashed the toolchain twice and stays blacklisted).
// R15 = R14's packed-pair slots (2 steps per dwordx4, 32-step lead, half the
// loads) + RENORM EVERY 16 STEPS (two renorms per 32-step body). R14's
// cadence-32 hit flush-to-zero (absmax inf): the s-max tracks the alignment
// path at ~e^-1/step below frame max, so a 32-step window bottoms out
// ~2^-46 and trailing columns cross the 2^-149 flush floor. Cadence 16 is
// the R11-proven safe window. s[t][j] = (s[j]+s[j-1]) * w[t][j], w<=1/2.
// ---------------------------------------------------------------------------
__device__ __forceinline__ float dpp_shr1_zero(float x) {
    int r = __builtin_amdgcn_update_dpp(
        0, __builtin_bit_cast(int, x), 0x138 /*wave_shr:1*/, 0xf, 0xf, false);
    return __builtin_bit_cast(float, r);
}

#define DPPMAX(M, CTRL, RM)                                               \
    do {                                                                  \
        int _t = __builtin_amdgcn_update_dpp(                             \
            __builtin_bit_cast(int, M), __builtin_bit_cast(int, M),       \
            CTRL, RM, 0xf, false);                                        \
        M = fmaxf(M, __builtin_bit_cast(float, _t));                      \
    } while (0)

#define GLOAD4(DST, PTR) \
    asm volatile("global_load_dwordx4 %0, %1, off" : "=v"(DST) : "v"(PTR))
#define VWAIT12(A,B,C,D2) \
    asm volatile("s_waitcnt vmcnt(12)" : "+v"(A), "+v"(B), "+v"(C), "+v"(D2))

__global__ __launch_bounds__(64) void scan_kernel(
    const float* __restrict__ wpk,         // (B, 65536) packed in ws
    const float* __restrict__ stash,       // (B,) musum
    const int* __restrict__ text_len, const int* __restrict__ mel_len,
    float* __restrict__ out0)
{
    const int b = blockIdx.x;
    const int l = threadIdx.x;
    const float* wb_ = wpk + (size_t)b * PKB_ + 4 * l;   // lane packet ptr
    const int Tend = mel_len[b], TendM1 = Tend - 1;      // Tend in [256,512]

    float s0 = (l == 0) ? 1.f : 0.f;   // s[t][j0], j0 = 2l
    float s1 = 0.f;                    // s[t][j1], j1 = 2l+1
    float fin0 = 0.f, fin1 = 0.f;
    int   shift_acc = 0, fsh = 0;
    int   t_cur = 1;
    int   p_pf  = 16;                  // next refill pair

    vf4 q0,q1,q2,q3,q4,q5,q6,q7,q8,q9,q10,q11,q12,q13,q14,q15;
    {
        const float* pp;
        #define INITQ(Q, P) pp = wb_ + (size_t)(P) * 256; GLOAD4(Q, pp)
        INITQ(q0,0);   INITQ(q1,1);   INITQ(q2,2);   INITQ(q3,3);
        INITQ(q4,4);   INITQ(q5,5);   INITQ(q6,6);   INITQ(q7,7);
        INITQ(q8,8);   INITQ(q9,9);   INITQ(q10,10); INITQ(q11,11);
        INITQ(q12,12); INITQ(q13,13); INITQ(q14,14); INITQ(q15,15);
        #undef INITQ
    }

    // one slot = two steps: (x,y) = odd-t half, (z,w) = even-t half
    #define CSTEP2(Q)                                        \
        do {                                                 \
            {                                                \
                float nb  = dpp_shr1_zero(s1);               \
                float ns0 = (s0 + nb) * (Q).x;               \
                float ns1 = (s1 + s0) * (Q).y;               \
                bool hit = (t_cur == TendM1);                \
                fin0 = hit ? ns0 : fin0;                     \
                fin1 = hit ? ns1 : fin1;                     \
                fsh  = hit ? shift_acc : fsh;                \
                s0 = ns0; s1 = ns1; ++t_cur;                 \
            }                                                \
            {                                                \
                float nb  = dpp_shr1_zero(s1);               \
                float ns0 = (s0 + nb) * (Q).z;               \
                float ns1 = (s1 + s0) * (Q).w;               \
                bool hit = (t_cur == TendM1);                \
                fin0 = hit ? ns0 : fin0;                     \
                fin1 = hit ? ns1 : fin1;                     \
                fsh  = hit ? shift_acc : fsh;                \
                s0 = ns0; s1 = ns1; ++t_cur;                 \
            }                                                \
        } while (0)

    #define REFILL(Q)                                        \
        do {                                                 \
            int rr = min(p_pf, 255);                         \
            const float* p_ = wb_ + (size_t)rr * 256;        \
            GLOAD4(Q, p_);                                   \
            ++p_pf;                                          \
        } while (0)

    #define GROUP(QA,QB,QC,QD)                               \
        do {                                                 \
            VWAIT12(QA,QB,QC,QD);                            \
            CSTEP2(QA); CSTEP2(QB); CSTEP2(QC); CSTEP2(QD);  \
            REFILL(QA); REFILL(QB); REFILL(QC); REFILL(QD);  \
        } while (0)

    #define RENORM                                                            \
        do {                                                                  \
            float mm = fmaxf(s0, s1);                                         \
            DPPMAX(mm, 0x111, 0xf);   /* row_shr:1 */                         \
            DPPMAX(mm, 0x112, 0xf);   /* row_shr:2 */                         \
            DPPMAX(mm, 0x114, 0xf);   /* row_shr:4 */                         \
            DPPMAX(mm, 0x118, 0xf);   /* row_shr:8 */                         \
            DPPMAX(mm, 0x142, 0xa);   /* row_bcast:15 -> rows 1,3 */          \
            DPPMAX(mm, 0x143, 0xc);   /* row_bcast:31 -> rows 2,3 */          \
            float M = __builtin_bit_cast(float,                               \
                __builtin_amdgcn_readlane(__builtin_bit_cast(int, mm), 63));  \
            if (M > 0.f) {                                                    \
                int e;                                                        \
                (void)frexpf(M, &e);                                          \
                float sc = ldexpf(1.f, -e);                                   \
                s0 *= sc; s1 *= sc;                                           \
                shift_acc += e;                                               \
            }                                                                 \
        } while (0)

    for (int t0 = 1; t0 <= TendM1; t0 += 32) {
        GROUP(q0,q1,q2,q3);   GROUP(q4,q5,q6,q7);
        RENORM;                                    // after 16 steps
        GROUP(q8,q9,q10,q11); GROUP(q12,q13,q14,q15);
        RENORM;                                    // after 32 steps
    }
    #undef CSTEP2
    #undef REFILL
    #undef GROUP
    #undef RENORM

    int jstar = text_len[b] - 1;                   // in [63,127]
    float vs = (jstar & 1) ? fin1 : fin0;
    int   vh = fsh;
    vs = __shfl(vs, jstar >> 1);
    vh = __shfl(vh, jstar >> 1);
    if (l == 0) {
        float musum = stash[b];
        float val   = __logf(vs) + (float)vh * LN2F + musum;
        atomicAdd(out0, -(val / (float)Tend) * (1.f / (float)B_));
    }
}

// ---------------------------------------------------------------------------
extern "C" void kernel_launch(void* const* d_in, const int* in_sizes, int n_in,
                              void* d_out, int out_size, void* d_ws, size_t ws_size,
                              hipStream_t stream) {
    const float* mu_logvar = (const float*)d_in[0];
    const float* melspec   = (const float*)d_in[1];
    const int*   text_len  = (const int*)d_in[2];
    const int*   mel_len   = (const int*)d_in[3];

    float* out    = (float*)d_out;      // out[0] = mdn_loss, out[1..] = lp
    float* lp_out = out + 1;
    float* wpk    = (float*)d_ws;                       // 4 MB packed weights
    float* stash  = (float*)d_ws + (size_t)B_ * PKB_;   // 16-float musum array

    dim3 g1(TXT_ / IT_, B_);
    lp_kernel<<<g1, MEL_, 0, stream>>>(mu_logvar, melspec, lp_out, stash, out);
    dim3 g2(MEL_ / 32, B_);
    wt_kernel<<<g2, 256, 0, stream>>>(lp_out, mel_len, wpk, stash);
    scan_kernel<<<B_, 64, 0, stream>>>(wpk, stash, text_len, mel_len, out);
}